// Round 1
// 307.928 us; speedup vs baseline: 1.0982x; 1.0982x over previous
//
#include <hip/hip_runtime.h>
#include <math.h>

// GAT 2-layer, N=100K nodes, E=1.6M edges (+N self loops), fp32 compute,
// f16 feature rows for the edge gather (was bf16).
// CSR build via 2-level bucket sort (bucket = dst>>8).
// agg RESTRUCTURED: 8 lanes per dst node, 8 nodes per wave.
//   - lane c of a group owns features 8c..8c+7 exclusively -> NO cross-lane
//     accumulator reduction, no zero-pad waste beyond 1 edge/node.
//   - edges processed in PAIRS: v_perm_b32 interleaves (h_e0[k], h_e1[k]) f16
//     halves, v_dot2_f32_f16 with packed (w0,w1) does 2 FMAs/instr, no unpack.
//   - sacc accumulated redundantly per-lane from the broadcast LDS pair.

constexpr int F_IN = 128;
constexpr int F_H  = 64;
constexpr int F_O  = 40;
constexpr int NBMAX = 512;      // max buckets (N <= 131072)
constexpr int CHUNK = 8192;     // edges per block in k_binC

using h2 = decltype(__builtin_amdgcn_cvt_pkrtz(0.f, 0.f));   // <2 x half>

__device__ __forceinline__ h2 u2h(unsigned u) { return __builtin_bit_cast(h2, u); }
__device__ __forceinline__ unsigned h2u(h2 h) { return __builtin_bit_cast(unsigned, h); }

__device__ __forceinline__ float fdot2f(h2 a, h2 b, float c) {
#if __has_builtin(__builtin_amdgcn_fdot2)
    return __builtin_amdgcn_fdot2(a, b, c, false);      // v_dot2_f32_f16
#else
    return c + (float)a.x * (float)b.x + (float)a.y * (float)b.y;
#endif
}
// interleave two u32s of packed f16 pairs: pklo -> (b.lo16, a.lo16), pkhi -> (b.hi16, a.hi16)
__device__ __forceinline__ h2 pklo(unsigned a, unsigned b) {
    return u2h(__builtin_amdgcn_perm(a, b, 0x05040100u));
}
__device__ __forceinline__ h2 pkhi(unsigned a, unsigned b) {
    return u2h(__builtin_amdgcn_perm(a, b, 0x07060302u));
}
__device__ __forceinline__ unsigned short f2h(float f) {   // RNE f32->f16 bits
    _Float16 x = (_Float16)f;
    return __builtin_bit_cast(unsigned short, x);
}

// ---------------- CSR build: bucket sort ----------------

__global__ __launch_bounds__(256) void k_binA(const int* __restrict__ dsts,
                                              int* __restrict__ bcnt,
                                              int E, int Et, int NB) {
    __shared__ int hist[NBMAX];
    for (int i = threadIdx.x; i < NB; i += 256) hist[i] = 0;
    __syncthreads();
    int e0 = blockIdx.x * 2048;
#pragma unroll
    for (int it = 0; it < 8; ++it) {
        int e = e0 + it * 256 + threadIdx.x;
        if (e < Et) {
            int d = (e < E) ? dsts[e] : (e - E);
            atomicAdd(&hist[d >> 8], 1);
        }
    }
    __syncthreads();
    for (int i = threadIdx.x; i < NB; i += 256) {
        int c = hist[i];
        if (c) atomicAdd(&bcnt[i], c);
    }
}

__global__ __launch_bounds__(NBMAX) void k_binB(const int* __restrict__ bcnt,
                                                int* __restrict__ bbase,
                                                int* __restrict__ bcur,
                                                int* __restrict__ rp,
                                                int NB, int N, int Et) {
    __shared__ int sc[NBMAX];
    int t = threadIdx.x;
    int v = (t < NB) ? bcnt[t] : 0;
    sc[t] = v; __syncthreads();
    int x = v;
    for (int o = 1; o < NBMAX; o <<= 1) {
        int y = (t >= o) ? sc[t - o] : 0;
        __syncthreads();
        x += y;
        sc[t] = x;
        __syncthreads();
    }
    if (t < NB) { int b = x - v; bbase[t] = b; bcur[t] = b; }
    if (t == 0) rp[N] = Et;
}

__global__ __launch_bounds__(256) void k_binC(const int* __restrict__ srcs,
                                              const int* __restrict__ dsts,
                                              int* __restrict__ bcur,
                                              unsigned* __restrict__ binned,
                                              int E, int Et, int NB) {
    __shared__ int hist[NBMAX];
    __shared__ int gbase[NBMAX];
    __shared__ int lcnt[NBMAX];
    int t = threadIdx.x;
    for (int i = t; i < NB; i += 256) hist[i] = 0;
    __syncthreads();
    int e0 = blockIdx.x * CHUNK;
#pragma unroll 4
    for (int it = 0; it < CHUNK / 256; ++it) {
        int e = e0 + it * 256 + t;
        if (e < Et) {
            int d = (e < E) ? dsts[e] : (e - E);
            atomicAdd(&hist[d >> 8], 1);
        }
    }
    __syncthreads();
    for (int i = t; i < NB; i += 256) {
        int c = hist[i];
        gbase[i] = c ? atomicAdd(&bcur[i], c) : 0;
        lcnt[i] = 0;
    }
    __syncthreads();
#pragma unroll 4
    for (int it = 0; it < CHUNK / 256; ++it) {
        int e = e0 + it * 256 + t;
        if (e < Et) {
            int s, d;
            if (e < E) { s = srcs[e]; d = dsts[e]; } else { s = e - E; d = s; }
            int b = d >> 8;
            int p = atomicAdd(&lcnt[b], 1);
            binned[gbase[b] + p] = (unsigned)s | ((unsigned)(d & 255) << 24);
        }
    }
}

__global__ __launch_bounds__(256) void k_binD(const unsigned* __restrict__ binned,
                                              const int* __restrict__ bbase,
                                              const int* __restrict__ bcur,
                                              int* __restrict__ rp,
                                              int* __restrict__ csr, int N) {
    __shared__ int hist[256];
    __shared__ int sc[256];
    __shared__ int lcnt[256];
    int b = blockIdx.x, t = threadIdx.x;
    int base = bbase[b], end = bcur[b];
    hist[t] = 0; __syncthreads();
    for (int j = base + t; j < end; j += 256)
        atomicAdd(&hist[binned[j] >> 24], 1);
    __syncthreads();
    int v = hist[t];
    sc[t] = v; __syncthreads();
    int x = v;
    for (int o = 1; o < 256; o <<= 1) {
        int y = (t >= o) ? sc[t - o] : 0;
        __syncthreads();
        x += y;
        sc[t] = x;
        __syncthreads();
    }
    int pref = x - v;
    int g = (b << 8) + t;
    if (g < N) rp[g] = base + pref;
    sc[t] = pref;
    lcnt[t] = 0;
    __syncthreads();
    for (int j = base + t; j < end; j += 256) {
        unsigned w = binned[j];
        int v2 = (int)(w >> 24);
        int s = (int)(w & 0xFFFFFFu);
        int p = atomicAdd(&lcnt[v2], 1);
        csr[base + sc[v2] + p] = s;
    }
}

// ---------------- GEMM1: h1 = f16(x @ W1), fused fp32 alphas ----------------

__global__ __launch_bounds__(256) void k_gemm1(const float* __restrict__ x,
                                               const float* __restrict__ W,
                                               const float* __restrict__ avs,
                                               const float* __restrict__ avd,
                                               unsigned short* __restrict__ h,
                                               float* __restrict__ as,
                                               float* __restrict__ ad, int N) {
    __shared__ __align__(16) float Ws[F_IN * F_H];
    for (int i = threadIdx.x; i < F_IN * F_H; i += 256) Ws[i] = W[i];
    __syncthreads();
    int t = threadIdx.x;
    int r0 = blockIdx.x * 64 + (t >> 4) * 4;
    int c0 = (t & 15) * 4;
    if (r0 >= N) return;
    const float* xp = x + (size_t)r0 * F_IN;
    float acc[4][4] = {};
    for (int k4 = 0; k4 < F_IN / 4; ++k4) {
        int kb = k4 * 4;
        float4 w0 = *(const float4*)&Ws[(kb + 0) * F_H + c0];
        float4 w1 = *(const float4*)&Ws[(kb + 1) * F_H + c0];
        float4 w2 = *(const float4*)&Ws[(kb + 2) * F_H + c0];
        float4 w3 = *(const float4*)&Ws[(kb + 3) * F_H + c0];
#pragma unroll
        for (int r = 0; r < 4; ++r) {
            float4 xv = *(const float4*)&xp[(size_t)r * F_IN + kb];
            acc[r][0] += xv.x * w0.x + xv.y * w1.x + xv.z * w2.x + xv.w * w3.x;
            acc[r][1] += xv.x * w0.y + xv.y * w1.y + xv.z * w2.y + xv.w * w3.y;
            acc[r][2] += xv.x * w0.z + xv.y * w1.z + xv.z * w2.z + xv.w * w3.z;
            acc[r][3] += xv.x * w0.w + xv.y * w1.w + xv.z * w2.w + xv.w * w3.w;
        }
    }
    float4 avs4 = *(const float4*)&avs[c0];
    float4 avd4 = *(const float4*)&avd[c0];
#pragma unroll
    for (int r = 0; r < 4; ++r) {
        unsigned lo = h2u(__builtin_amdgcn_cvt_pkrtz(acc[r][0], acc[r][1]));
        unsigned hi = h2u(__builtin_amdgcn_cvt_pkrtz(acc[r][2], acc[r][3]));
        ((uint2*)h)[((size_t)(r0 + r) * F_H + c0) >> 2] = make_uint2(lo, hi);
        float ps = acc[r][0] * avs4.x + acc[r][1] * avs4.y + acc[r][2] * avs4.z + acc[r][3] * avs4.w;
        float pd = acc[r][0] * avd4.x + acc[r][1] * avd4.y + acc[r][2] * avd4.z + acc[r][3] * avd4.w;
#pragma unroll
        for (int o = 8; o; o >>= 1) {
            ps += __shfl_xor(ps, o, 16);
            pd += __shfl_xor(pd, o, 16);
        }
        if ((t & 15) == 0) { as[r0 + r] = ps; ad[r0 + r] = pd; }
    }
}

// ---------------- GEMM2: h2 = f16(out1 @ W2) padded to 64 cols ----------------

__global__ __launch_bounds__(256) void k_gemm2(const float* __restrict__ xin,
                                               const float* __restrict__ W,
                                               const float* __restrict__ avs,
                                               const float* __restrict__ avd,
                                               unsigned short* __restrict__ h,
                                               float* __restrict__ as,
                                               float* __restrict__ ad, int N) {
    __shared__ __align__(16) float Ws[F_H * F_O];
    for (int i = threadIdx.x; i < F_H * F_O; i += 256) Ws[i] = W[i];
    __syncthreads();
    int t = threadIdx.x;
    int r0 = blockIdx.x * 64 + (t >> 3) * 2;
    int l = t & 7;
    if (r0 >= N) return;
    const float4* xa = (const float4*)(xin + (size_t)r0 * F_H);
    const float4* xb = (const float4*)(xin + (size_t)(r0 + 1) * F_H);
    float acca[5] = {}, accb[5] = {};
#pragma unroll
    for (int k4 = 0; k4 < F_H / 4; ++k4) {
        float4 xva = xa[k4];
        float4 xvb = xb[k4];
        int kb = k4 * 4;
#pragma unroll
        for (int kk = 0; kk < 4; ++kk) {
            const float* wr = &Ws[(kb + kk) * F_O + l];
            float w0 = wr[0], w1 = wr[8], w2 = wr[16], w3 = wr[24], w4 = wr[32];
            float xs = (&xva.x)[kk];
            acca[0] += xs * w0; acca[1] += xs * w1; acca[2] += xs * w2;
            acca[3] += xs * w3; acca[4] += xs * w4;
            float ys = (&xvb.x)[kk];
            accb[0] += ys * w0; accb[1] += ys * w1; accb[2] += ys * w2;
            accb[3] += ys * w3; accb[4] += ys * w4;
        }
    }
    float psa = 0.f, pda = 0.f, psb = 0.f, pdb = 0.f;
    unsigned short* ra = h + (size_t)r0 * F_H;     // padded row stride 64
    unsigned short* rb = h + (size_t)(r0 + 1) * F_H;
#pragma unroll
    for (int cc = 0; cc < 5; ++cc) {
        int c = l + 8 * cc;
        ra[c] = f2h(acca[cc]);
        rb[c] = f2h(accb[cc]);
        float vs = avs[c], vd = avd[c];
        psa += acca[cc] * vs; pda += acca[cc] * vd;
        psb += accb[cc] * vs; pdb += accb[cc] * vd;
    }
#pragma unroll
    for (int pp = 0; pp < 3; ++pp) {               // zero pad cols 40..63
        int c = 40 + l * 3 + pp;
        ra[c] = 0; rb[c] = 0;
    }
#pragma unroll
    for (int o = 4; o; o >>= 1) {
        psa += __shfl_xor(psa, o, 8);
        pda += __shfl_xor(pda, o, 8);
        psb += __shfl_xor(psb, o, 8);
        pdb += __shfl_xor(pdb, o, 8);
    }
    if (l == 0) { as[r0] = psa; ad[r0] = pda; as[r0 + 1] = psb; ad[r0 + 1] = pdb; }
}

// ---------------- Aggregation: 8 lanes per dst node, 8 nodes per wave ----------------
// Group = 8 lanes; lane c owns features 8c..8c+7 (one uint4 = 8 f16 per row).
// Phase A: group's lanes compute w=exp(leaky(as[src]+ad[i])) strided, store
// (w_bits, src) uint2 into the group's LDS segment (no barrier: same-wave LDS).
// Phase B: edges in PAIRS. One ds_read_b128 broadcasts (w0,s0,w1,s1) to the
// group; two uint4 gathers fetch both rows' feature chunks; v_cvt_pkrtz packs
// (w0,w1); v_perm_b32 interleaves f16 halves; v_dot2_f32_f16 accumulates
// 2 edges/feature/instr in fp32. sacc accumulated redundantly in every lane
// (identical values) -> no cross-lane reductions at all for the weighted sum.

template <int FOUT, bool RELU, bool LOGSM>
__global__ __launch_bounds__(256) void k_agg(const int* __restrict__ rp,
                                             const int* __restrict__ csr,
                                             const float* __restrict__ as,
                                             const float* __restrict__ ad,
                                             const uint4* __restrict__ h4,
                                             const float* __restrict__ bias,
                                             float* __restrict__ out, int N) {
    constexpr int CAP = 64;                        // LDS-resident edges per node
    __shared__ __align__(16) uint2 wsb[4][8][CAP + 2];  // +2: pad slot + 16B de-conflict stride
    const int w = threadIdx.x >> 6;
    const int g = (threadIdx.x >> 3) & 7;
    const int c = threadIdx.x & 7;
    const int i = blockIdx.x * 32 + (threadIdx.x >> 3);
    if (i >= N) return;
    const int start = rp[i], end = rp[i + 1];
    const int deg = end - start;
    const int dm = min(deg, CAP);
    const float adi = ad[i];

    // Phase A: compute edge weights into this group's LDS segment
    for (int idx = c; idx < dm; idx += 8) {
        int srcn = csr[start + idx];
        float e = as[srcn] + adi;
        e = fmaxf(e, 0.2f * e);                    // leaky_relu
        wsb[w][g][idx] = make_uint2(__float_as_uint(__expf(e)), (unsigned)srcn);
    }
    if (c == 0 && (dm & 1))                        // pad to even: w=0, src=self
        wsb[w][g][dm] = make_uint2(0u, (unsigned)i);

    // Phase B: pair loop (same-wave LDS, no barrier needed)
    const uint4* pw = (const uint4*)wsb[w][g];
    float acc[8] = {};
    float sacc = 0.f;
    const int npair = (dm + 1) >> 1;
    for (int p = 0; p < npair; ++p) {
        uint4 t = pw[p];                           // (w0,s0,w1,s1) broadcast to group
        float w0 = __uint_as_float(t.x), w1 = __uint_as_float(t.z);
        sacc += w0 + w1;
        uint4 hv0 = h4[((unsigned)t.y << 3) + c];
        uint4 hv1 = h4[((unsigned)t.w << 3) + c];
        h2 wp = __builtin_amdgcn_cvt_pkrtz(w0, w1);
        acc[0] = fdot2f(wp, pklo(hv1.x, hv0.x), acc[0]);
        acc[1] = fdot2f(wp, pkhi(hv1.x, hv0.x), acc[1]);
        acc[2] = fdot2f(wp, pklo(hv1.y, hv0.y), acc[2]);
        acc[3] = fdot2f(wp, pkhi(hv1.y, hv0.y), acc[3]);
        acc[4] = fdot2f(wp, pklo(hv1.z, hv0.z), acc[4]);
        acc[5] = fdot2f(wp, pkhi(hv1.z, hv0.z), acc[5]);
        acc[6] = fdot2f(wp, pklo(hv1.w, hv0.w), acc[6]);
        acc[7] = fdot2f(wp, pkhi(hv1.w, hv0.w), acc[7]);
    }

    // rare overflow tail (deg > CAP): single-edge, dup-pair trick with (w,0)
    for (int j = start + dm; j < end; ++j) {
        int srcn = csr[j];
        float e = as[srcn] + adi;
        e = fmaxf(e, 0.2f * e);
        float wv = __expf(e);
        sacc += wv;
        uint4 hv = h4[((unsigned)srcn << 3) + c];
        h2 wp = __builtin_amdgcn_cvt_pkrtz(wv, 0.f);
        acc[0] = fdot2f(wp, pklo(hv.x, hv.x), acc[0]);
        acc[1] = fdot2f(wp, pkhi(hv.x, hv.x), acc[1]);
        acc[2] = fdot2f(wp, pklo(hv.y, hv.y), acc[2]);
        acc[3] = fdot2f(wp, pkhi(hv.y, hv.y), acc[3]);
        acc[4] = fdot2f(wp, pklo(hv.z, hv.z), acc[4]);
        acc[5] = fdot2f(wp, pkhi(hv.z, hv.z), acc[5]);
        acc[6] = fdot2f(wp, pklo(hv.w, hv.w), acc[6]);
        acc[7] = fdot2f(wp, pkhi(hv.w, hv.w), acc[7]);
    }

    float inv = 1.f / sacc;                        // identical across the group

    if (!LOGSM) {
        float r[8];
#pragma unroll
        for (int k = 0; k < 8; ++k) {
            r[k] = fmaf(acc[k], inv, bias[8 * c + k]);
            if (RELU) r[k] = fmaxf(r[k], 0.f);
        }
        float4* op = (float4*)(out + (size_t)i * FOUT + 8 * c);
        op[0] = make_float4(r[0], r[1], r[2], r[3]);
        op[1] = make_float4(r[4], r[5], r[6], r[7]);
    } else {
        constexpr int VC = FOUT / 8;               // valid lane-chunks (5 for FOUT=40)
        bool act = (c < VC);
        float v[8];
#pragma unroll
        for (int k = 0; k < 8; ++k) {
            float bv = bias[act ? 8 * c + k : 0];
            v[k] = act ? fmaf(acc[k], inv, bv) : -INFINITY;
        }
        float mx = v[0];
#pragma unroll
        for (int k = 1; k < 8; ++k) mx = fmaxf(mx, v[k]);
#pragma unroll
        for (int o = 1; o <= 4; o <<= 1) mx = fmaxf(mx, __shfl_xor(mx, o));  // within 8-lane group
        float es = 0.f;
        if (act) {
#pragma unroll
            for (int k = 0; k < 8; ++k) es += __expf(v[k] - mx);
        }
#pragma unroll
        for (int o = 1; o <= 4; o <<= 1) es += __shfl_xor(es, o);
        if (act) {
            float lse = mx + __logf(es);
            float4* op = (float4*)(out + (size_t)i * FOUT + 8 * c);
            op[0] = make_float4(v[0] - lse, v[1] - lse, v[2] - lse, v[3] - lse);
            op[1] = make_float4(v[4] - lse, v[5] - lse, v[6] - lse, v[7] - lse);
        }
    }
}

// ---------------- launch ----------------

extern "C" void kernel_launch(void* const* d_in, const int* in_sizes, int n_in,
                              void* d_out, int out_size, void* d_ws, size_t ws_size,
                              hipStream_t stream) {
    const float* x   = (const float*)d_in[0];
    const int* edges = (const int*)d_in[1];
    const float* W1  = (const float*)d_in[2];
    const float* av_s1 = (const float*)d_in[3];
    const float* av_d1 = (const float*)d_in[4];
    const float* b1  = (const float*)d_in[5];
    const float* W2  = (const float*)d_in[6];
    const float* av_s2 = (const float*)d_in[7];
    const float* av_d2 = (const float*)d_in[8];
    const float* b2  = (const float*)d_in[9];
    float* out = (float*)d_out;

    const int N  = in_sizes[0] / F_IN;
    const int E  = in_sizes[1] / 2;
    const int Et = E + N;
    const int NB = (N + 255) >> 8;

    char* p = (char*)d_ws;
    auto alloc = [&](size_t bytes) {
        char* q = p;
        p += (bytes + 255) & ~(size_t)255;
        return (void*)q;
    };
    unsigned short* h1 = (unsigned short*)alloc((size_t)N * F_H * 2);  // f16; reused as h2 (padded to 64)
    float* out1   = (float*)alloc((size_t)N * F_H * 4);
    float* as1    = (float*)alloc((size_t)N * 4);
    float* ad1    = (float*)alloc((size_t)N * 4);
    float* as2    = (float*)alloc((size_t)N * 4);
    float* ad2    = (float*)alloc((size_t)N * 4);
    int* rp       = (int*)alloc((size_t)(N + 1) * 4);
    int* bcnt     = (int*)alloc(NBMAX * 4);
    int* bbase    = (int*)alloc(NBMAX * 4);
    int* bcur     = (int*)alloc(NBMAX * 4);
    unsigned* binned = (unsigned*)alloc((size_t)Et * 4);
    int* csr      = (int*)alloc((size_t)Et * 4);
    (void)n_in; (void)out_size; (void)ws_size;

    const int* srcs = edges;
    const int* dsts = edges + E;

    hipMemsetAsync(bcnt, 0, NBMAX * 4, stream);

    k_binA<<<(Et + 2047) / 2048, 256, 0, stream>>>(dsts, bcnt, E, Et, NB);
    k_binB<<<1, NBMAX, 0, stream>>>(bcnt, bbase, bcur, rp, NB, N, Et);
    k_binC<<<(Et + CHUNK - 1) / CHUNK, 256, 0, stream>>>(srcs, dsts, bcur, binned, E, Et, NB);
    k_binD<<<NB, 256, 0, stream>>>(binned, bbase, bcur, rp, csr, N);

    k_gemm1<<<(N + 63) / 64, 256, 0, stream>>>(x, W1, av_s1, av_d1, h1, as1, ad1, N);
    int gAgg = (N + 31) / 32;
    k_agg<F_H, true, false><<<gAgg, 256, 0, stream>>>(rp, csr, as1, ad1,
                                                      (const uint4*)h1, b1, out1, N);
    k_gemm2<<<(N + 63) / 64, 256, 0, stream>>>(out1, W2, av_s2, av_d2, h1, as2, ad2, N);
    k_agg<F_O, false, true><<<gAgg, 256, 0, stream>>>(rp, csr, as2, ad2,
                                                      (const uint4*)h1, b2, out, N);
}

// Round 2
// 295.960 us; speedup vs baseline: 1.1426x; 1.0404x over previous
//
#include <hip/hip_runtime.h>
#include <math.h>

// GAT 2-layer, N=100K nodes, E=1.6M edges (+N self loops), fp32 compute,
// f16 feature rows for the edge gather.
// CSR build via 2-level bucket sort (bucket = dst>>8).
// agg: 8 lanes per dst node, 8 nodes per wave, f16 pair-dot (v_dot2_f32_f16).
// gemm1 NOW MFMA: 3-pass truncation-split bf16 (x_hi@W_hi + x_lo@W_hi +
//   x_hi@W_lo), error ~2^-16 rel << f16 storage rounding. x loaded directly
//   global->A-frags (no LDS staging, no redundant reads); W pre-split and
//   transposed by k_wsplit into B-frag-contiguous [64][128] u16 arrays.

constexpr int F_IN = 128;
constexpr int F_H  = 64;
constexpr int F_O  = 40;
constexpr int NBMAX = 512;      // max buckets (N <= 131072)
constexpr int CHUNK = 8192;     // edges per block in k_binC

using h2 = decltype(__builtin_amdgcn_cvt_pkrtz(0.f, 0.f));   // <2 x half>
typedef __attribute__((ext_vector_type(4))) float f32x4;
typedef __attribute__((ext_vector_type(8))) short s16x8;

__device__ __forceinline__ h2 u2h(unsigned u) { return __builtin_bit_cast(h2, u); }

__device__ __forceinline__ float fdot2f(h2 a, h2 b, float c) {
#if __has_builtin(__builtin_amdgcn_fdot2)
    return __builtin_amdgcn_fdot2(a, b, c, false);      // v_dot2_f32_f16
#else
    return c + (float)a.x * (float)b.x + (float)a.y * (float)b.y;
#endif
}
// interleave two u32s of packed f16 pairs: pklo -> (b.lo16, a.lo16), pkhi -> (b.hi16, a.hi16)
__device__ __forceinline__ h2 pklo(unsigned a, unsigned b) {
    return u2h(__builtin_amdgcn_perm(a, b, 0x05040100u));
}
__device__ __forceinline__ h2 pkhi(unsigned a, unsigned b) {
    return u2h(__builtin_amdgcn_perm(a, b, 0x07060302u));
}
__device__ __forceinline__ unsigned short f2h(float f) {   // RNE f32->f16 bits
    _Float16 x = (_Float16)f;
    return __builtin_bit_cast(unsigned short, x);
}

// ---------------- CSR build: bucket sort ----------------

__global__ __launch_bounds__(256) void k_binA(const int* __restrict__ dsts,
                                              int* __restrict__ bcnt,
                                              int E, int Et, int NB) {
    __shared__ int hist[NBMAX];
    for (int i = threadIdx.x; i < NB; i += 256) hist[i] = 0;
    __syncthreads();
    int e0 = blockIdx.x * 2048;
#pragma unroll
    for (int it = 0; it < 8; ++it) {
        int e = e0 + it * 256 + threadIdx.x;
        if (e < Et) {
            int d = (e < E) ? dsts[e] : (e - E);
            atomicAdd(&hist[d >> 8], 1);
        }
    }
    __syncthreads();
    for (int i = threadIdx.x; i < NB; i += 256) {
        int c = hist[i];
        if (c) atomicAdd(&bcnt[i], c);
    }
}

__global__ __launch_bounds__(NBMAX) void k_binB(const int* __restrict__ bcnt,
                                                int* __restrict__ bbase,
                                                int* __restrict__ bcur,
                                                int* __restrict__ rp,
                                                int NB, int N, int Et) {
    __shared__ int sc[NBMAX];
    int t = threadIdx.x;
    int v = (t < NB) ? bcnt[t] : 0;
    sc[t] = v; __syncthreads();
    int x = v;
    for (int o = 1; o < NBMAX; o <<= 1) {
        int y = (t >= o) ? sc[t - o] : 0;
        __syncthreads();
        x += y;
        sc[t] = x;
        __syncthreads();
    }
    if (t < NB) { int b = x - v; bbase[t] = b; bcur[t] = b; }
    if (t == 0) rp[N] = Et;
}

__global__ __launch_bounds__(256) void k_binC(const int* __restrict__ srcs,
                                              const int* __restrict__ dsts,
                                              int* __restrict__ bcur,
                                              unsigned* __restrict__ binned,
                                              int E, int Et, int NB) {
    __shared__ int hist[NBMAX];
    __shared__ int gbase[NBMAX];
    __shared__ int lcnt[NBMAX];
    int t = threadIdx.x;
    for (int i = t; i < NB; i += 256) hist[i] = 0;
    __syncthreads();
    int e0 = blockIdx.x * CHUNK;
#pragma unroll 4
    for (int it = 0; it < CHUNK / 256; ++it) {
        int e = e0 + it * 256 + t;
        if (e < Et) {
            int d = (e < E) ? dsts[e] : (e - E);
            atomicAdd(&hist[d >> 8], 1);
        }
    }
    __syncthreads();
    for (int i = t; i < NB; i += 256) {
        int c = hist[i];
        gbase[i] = c ? atomicAdd(&bcur[i], c) : 0;
        lcnt[i] = 0;
    }
    __syncthreads();
#pragma unroll 4
    for (int it = 0; it < CHUNK / 256; ++it) {
        int e = e0 + it * 256 + t;
        if (e < Et) {
            int s, d;
            if (e < E) { s = srcs[e]; d = dsts[e]; } else { s = e - E; d = s; }
            int b = d >> 8;
            int p = atomicAdd(&lcnt[b], 1);
            binned[gbase[b] + p] = (unsigned)s | ((unsigned)(d & 255) << 24);
        }
    }
}

__global__ __launch_bounds__(256) void k_binD(const unsigned* __restrict__ binned,
                                              const int* __restrict__ bbase,
                                              const int* __restrict__ bcur,
                                              int* __restrict__ rp,
                                              int* __restrict__ csr, int N) {
    __shared__ int hist[256];
    __shared__ int sc[256];
    __shared__ int lcnt[256];
    int b = blockIdx.x, t = threadIdx.x;
    int base = bbase[b], end = bcur[b];
    hist[t] = 0; __syncthreads();
    for (int j = base + t; j < end; j += 256)
        atomicAdd(&hist[binned[j] >> 24], 1);
    __syncthreads();
    int v = hist[t];
    sc[t] = v; __syncthreads();
    int x = v;
    for (int o = 1; o < 256; o <<= 1) {
        int y = (t >= o) ? sc[t - o] : 0;
        __syncthreads();
        x += y;
        sc[t] = x;
        __syncthreads();
    }
    int pref = x - v;
    int g = (b << 8) + t;
    if (g < N) rp[g] = base + pref;
    sc[t] = pref;
    lcnt[t] = 0;
    __syncthreads();
    for (int j = base + t; j < end; j += 256) {
        unsigned w = binned[j];
        int v2 = (int)(w >> 24);
        int s = (int)(w & 0xFFFFFFu);
        int p = atomicAdd(&lcnt[v2], 1);
        csr[base + sc[v2] + p] = s;
    }
}

// ---------------- W1 split: fp32 [128][64] -> bf16-hi/lo transposed [64][128] ----------------

__global__ __launch_bounds__(256) void k_wsplit(const float* __restrict__ W,
                                                unsigned short* __restrict__ WhiT,
                                                unsigned short* __restrict__ WloT) {
    int i = blockIdx.x * 256 + threadIdx.x;
    if (i >= F_IN * F_H) return;
    int k = i >> 6, c = i & 63;                    // W[k][c], C = F_H = 64
    float w = W[i];
    unsigned u = __float_as_uint(w);
    unsigned hi = u & 0xFFFF0000u;                 // truncation split: residual
    float d = w - __uint_as_float(hi);             // captured exactly by lo
    WhiT[c * F_IN + k] = (unsigned short)(hi >> 16);
    WloT[c * F_IN + k] = (unsigned short)(__float_as_uint(d) >> 16);
}

// ---------------- GEMM1 (MFMA): h1 = f16(x @ W1), fused fp32 alphas ----------------
// Block: 64 rows, 4 waves x 16 rows. Per wave: 4 col-tiles x 4 K-tiles x 3
// passes = 48 v_mfma_f32_16x16x32_bf16. A-frags straight from global x
// (row = lane&15, k = (lane>>4)*8+j), split hi/lo in-register (3 VALU/elem
// via v_perm). B-frags from WhiT/WloT (contiguous 16B, L1/L2-hot). C layout:
// col = lane&15, row = (lane>>4)*4+reg. Output staged through 9KB LDS for
// coalesced 32B/thread f16 stores.

__global__ __launch_bounds__(256) void k_gemm1m(const float* __restrict__ x,
                                                const unsigned short* __restrict__ WhiT,
                                                const unsigned short* __restrict__ WloT,
                                                const float* __restrict__ avs,
                                                const float* __restrict__ avd,
                                                unsigned short* __restrict__ h,
                                                float* __restrict__ as,
                                                float* __restrict__ ad, int N) {
    __shared__ unsigned short hs[64][72];          // 72: bank-stagger, 16B-aligned rows
    const int t = threadIdx.x;
    const int wv = t >> 6;
    const int lane = t & 63;
    const int lrow = lane & 15;
    const int lk8 = lane >> 4;
    const int r0 = blockIdx.x * 64;
    const int arow = r0 + wv * 16 + lrow;
    const float* xp = x + (size_t)min(arow, N - 1) * F_IN;

    // preload full row slice (8 float4), then split to bf16 hi/lo A-frags
    float4 xv0[4], xv1[4];
#pragma unroll
    for (int kt = 0; kt < 4; ++kt) {
        xv0[kt] = *(const float4*)&xp[kt * 32 + lk8 * 8];
        xv1[kt] = *(const float4*)&xp[kt * 32 + lk8 * 8 + 4];
    }
    s16x8 ah[4], al[4];
#pragma unroll
    for (int kt = 0; kt < 4; ++kt) {
        float e0[8] = {xv0[kt].x, xv0[kt].y, xv0[kt].z, xv0[kt].w,
                       xv1[kt].x, xv1[kt].y, xv1[kt].z, xv1[kt].w};
        unsigned uh[4], ul[4];
#pragma unroll
        for (int p = 0; p < 4; ++p) {
            float a0 = e0[2 * p], a1 = e0[2 * p + 1];
            unsigned u0 = __float_as_uint(a0), u1 = __float_as_uint(a1);
            float d0 = a0 - __uint_as_float(u0 & 0xFFFF0000u);
            float d1 = a1 - __uint_as_float(u1 & 0xFFFF0000u);
            uh[p] = __builtin_amdgcn_perm(u1, u0, 0x07060302u);
            ul[p] = __builtin_amdgcn_perm(__float_as_uint(d1), __float_as_uint(d0), 0x07060302u);
        }
        ah[kt] = __builtin_bit_cast(s16x8, make_uint4(uh[0], uh[1], uh[2], uh[3]));
        al[kt] = __builtin_bit_cast(s16x8, make_uint4(ul[0], ul[1], ul[2], ul[3]));
    }

    f32x4 acc[4] = {};                             // one 16x16 C-tile per ct
#pragma unroll
    for (int kt = 0; kt < 4; ++kt) {
#pragma unroll
        for (int ct = 0; ct < 4; ++ct) {
            const int boff = (ct * 16 + lrow) * F_IN + kt * 32 + lk8 * 8;
            s16x8 bh = *(const s16x8*)&WhiT[boff];
            s16x8 bl = *(const s16x8*)&WloT[boff];
            acc[ct] = __builtin_amdgcn_mfma_f32_16x16x32_bf16(ah[kt], bh, acc[ct], 0, 0, 0);
            acc[ct] = __builtin_amdgcn_mfma_f32_16x16x32_bf16(al[kt], bh, acc[ct], 0, 0, 0);
            acc[ct] = __builtin_amdgcn_mfma_f32_16x16x32_bf16(ah[kt], bl, acc[ct], 0, 0, 0);
        }
    }

    // fused alphas from fp32 accumulators: reduce over 16 cols (lrow groups)
    float avs_c[4], avd_c[4];
#pragma unroll
    for (int ct = 0; ct < 4; ++ct) {
        avs_c[ct] = avs[ct * 16 + lrow];
        avd_c[ct] = avd[ct * 16 + lrow];
    }
#pragma unroll
    for (int r = 0; r < 4; ++r) {
        float ps = acc[0][r] * avs_c[0] + acc[1][r] * avs_c[1]
                 + acc[2][r] * avs_c[2] + acc[3][r] * avs_c[3];
        float pd = acc[0][r] * avd_c[0] + acc[1][r] * avd_c[1]
                 + acc[2][r] * avd_c[2] + acc[3][r] * avd_c[3];
#pragma unroll
        for (int o = 8; o; o >>= 1) {
            ps += __shfl_xor(ps, o, 16);
            pd += __shfl_xor(pd, o, 16);
        }
        int orow = r0 + wv * 16 + lk8 * 4 + r;
        if (lrow == 0 && orow < N) { as[orow] = ps; ad[orow] = pd; }
    }

    // C -> LDS (f16) -> coalesced global store
#pragma unroll
    for (int ct = 0; ct < 4; ++ct)
#pragma unroll
        for (int r = 0; r < 4; ++r)
            hs[wv * 16 + lk8 * 4 + r][ct * 16 + lrow] = f2h(acc[ct][r]);
    __syncthreads();
    const int row = t >> 2, ch = t & 3;
    const int grow = r0 + row;
    if (grow < N) {
        uint4 v0 = *(const uint4*)&hs[row][ch * 16];
        uint4 v1 = *(const uint4*)&hs[row][ch * 16 + 8];
        uint4* gp = (uint4*)(h + (size_t)grow * F_H + ch * 16);
        gp[0] = v0; gp[1] = v1;
    }
}

// ---------------- GEMM2: h2 = f16(out1 @ W2) padded to 64 cols ----------------

__global__ __launch_bounds__(256) void k_gemm2(const float* __restrict__ xin,
                                               const float* __restrict__ W,
                                               const float* __restrict__ avs,
                                               const float* __restrict__ avd,
                                               unsigned short* __restrict__ h,
                                               float* __restrict__ as,
                                               float* __restrict__ ad, int N) {
    __shared__ __align__(16) float Ws[F_H * F_O];
    for (int i = threadIdx.x; i < F_H * F_O; i += 256) Ws[i] = W[i];
    __syncthreads();
    int t = threadIdx.x;
    int r0 = blockIdx.x * 64 + (t >> 3) * 2;
    int l = t & 7;
    if (r0 >= N) return;
    const float4* xa = (const float4*)(xin + (size_t)r0 * F_H);
    const float4* xb = (const float4*)(xin + (size_t)(r0 + 1) * F_H);
    float acca[5] = {}, accb[5] = {};
#pragma unroll
    for (int k4 = 0; k4 < F_H / 4; ++k4) {
        float4 xva = xa[k4];
        float4 xvb = xb[k4];
        int kb = k4 * 4;
#pragma unroll
        for (int kk = 0; kk < 4; ++kk) {
            const float* wr = &Ws[(kb + kk) * F_O + l];
            float w0 = wr[0], w1 = wr[8], w2 = wr[16], w3 = wr[24], w4 = wr[32];
            float xs = (&xva.x)[kk];
            acca[0] += xs * w0; acca[1] += xs * w1; acca[2] += xs * w2;
            acca[3] += xs * w3; acca[4] += xs * w4;
            float ys = (&xvb.x)[kk];
            accb[0] += ys * w0; accb[1] += ys * w1; accb[2] += ys * w2;
            accb[3] += ys * w3; accb[4] += ys * w4;
        }
    }
    float psa = 0.f, pda = 0.f, psb = 0.f, pdb = 0.f;
    unsigned short* ra = h + (size_t)r0 * F_H;     // padded row stride 64
    unsigned short* rb = h + (size_t)(r0 + 1) * F_H;
#pragma unroll
    for (int cc = 0; cc < 5; ++cc) {
        int c = l + 8 * cc;
        ra[c] = f2h(acca[cc]);
        rb[c] = f2h(accb[cc]);
        float vs = avs[c], vd = avd[c];
        psa += acca[cc] * vs; pda += acca[cc] * vd;
        psb += accb[cc] * vs; pdb += accb[cc] * vd;
    }
#pragma unroll
    for (int pp = 0; pp < 3; ++pp) {               // zero pad cols 40..63
        int c = 40 + l * 3 + pp;
        ra[c] = 0; rb[c] = 0;
    }
#pragma unroll
    for (int o = 4; o; o >>= 1) {
        psa += __shfl_xor(psa, o, 8);
        pda += __shfl_xor(pda, o, 8);
        psb += __shfl_xor(psb, o, 8);
        pdb += __shfl_xor(pdb, o, 8);
    }
    if (l == 0) { as[r0] = psa; ad[r0] = pda; as[r0 + 1] = psb; ad[r0 + 1] = pdb; }
}

// ---------------- Aggregation: 8 lanes per dst node, 8 nodes per wave ----------------

template <int FOUT, bool RELU, bool LOGSM>
__global__ __launch_bounds__(256) void k_agg(const int* __restrict__ rp,
                                             const int* __restrict__ csr,
                                             const float* __restrict__ as,
                                             const float* __restrict__ ad,
                                             const uint4* __restrict__ h4,
                                             const float* __restrict__ bias,
                                             float* __restrict__ out, int N) {
    constexpr int CAP = 64;                        // LDS-resident edges per node
    __shared__ __align__(16) uint2 wsb[4][8][CAP + 2];  // +2: pad slot + 16B de-conflict stride
    const int w = threadIdx.x >> 6;
    const int g = (threadIdx.x >> 3) & 7;
    const int c = threadIdx.x & 7;
    const int i = blockIdx.x * 32 + (threadIdx.x >> 3);
    if (i >= N) return;
    const int start = rp[i], end = rp[i + 1];
    const int deg = end - start;
    const int dm = min(deg, CAP);
    const float adi = ad[i];

    // Phase A: compute edge weights into this group's LDS segment
    for (int idx = c; idx < dm; idx += 8) {
        int srcn = csr[start + idx];
        float e = as[srcn] + adi;
        e = fmaxf(e, 0.2f * e);                    // leaky_relu
        wsb[w][g][idx] = make_uint2(__float_as_uint(__expf(e)), (unsigned)srcn);
    }
    if (c == 0 && (dm & 1))                        // pad to even: w=0, src=self
        wsb[w][g][dm] = make_uint2(0u, (unsigned)i);

    // Phase B: pair loop (same-wave LDS, no barrier needed)
    const uint4* pw = (const uint4*)wsb[w][g];
    float acc[8] = {};
    float sacc = 0.f;
    const int npair = (dm + 1) >> 1;
    for (int p = 0; p < npair; ++p) {
        uint4 t = pw[p];                           // (w0,s0,w1,s1) broadcast to group
        float w0 = __uint_as_float(t.x), w1 = __uint_as_float(t.z);
        sacc += w0 + w1;
        uint4 hv0 = h4[((unsigned)t.y << 3) + c];
        uint4 hv1 = h4[((unsigned)t.w << 3) + c];
        h2 wp = __builtin_amdgcn_cvt_pkrtz(w0, w1);
        acc[0] = fdot2f(wp, pklo(hv1.x, hv0.x), acc[0]);
        acc[1] = fdot2f(wp, pkhi(hv1.x, hv0.x), acc[1]);
        acc[2] = fdot2f(wp, pklo(hv1.y, hv0.y), acc[2]);
        acc[3] = fdot2f(wp, pkhi(hv1.y, hv0.y), acc[3]);
        acc[4] = fdot2f(wp, pklo(hv1.z, hv0.z), acc[4]);
        acc[5] = fdot2f(wp, pkhi(hv1.z, hv0.z), acc[5]);
        acc[6] = fdot2f(wp, pklo(hv1.w, hv0.w), acc[6]);
        acc[7] = fdot2f(wp, pkhi(hv1.w, hv0.w), acc[7]);
    }

    // rare overflow tail (deg > CAP): single-edge, dup-pair trick with (w,0)
    for (int j = start + dm; j < end; ++j) {
        int srcn = csr[j];
        float e = as[srcn] + adi;
        e = fmaxf(e, 0.2f * e);
        float wv = __expf(e);
        sacc += wv;
        uint4 hv = h4[((unsigned)srcn << 3) + c];
        h2 wp = __builtin_amdgcn_cvt_pkrtz(wv, 0.f);
        acc[0] = fdot2f(wp, pklo(hv.x, hv.x), acc[0]);
        acc[1] = fdot2f(wp, pkhi(hv.x, hv.x), acc[1]);
        acc[2] = fdot2f(wp, pklo(hv.y, hv.y), acc[2]);
        acc[3] = fdot2f(wp, pkhi(hv.y, hv.y), acc[3]);
        acc[4] = fdot2f(wp, pklo(hv.z, hv.z), acc[4]);
        acc[5] = fdot2f(wp, pkhi(hv.z, hv.z), acc[5]);
        acc[6] = fdot2f(wp, pklo(hv.w, hv.w), acc[6]);
        acc[7] = fdot2f(wp, pkhi(hv.w, hv.w), acc[7]);
    }

    float inv = 1.f / sacc;                        // identical across the group

    if (!LOGSM) {
        float r[8];
#pragma unroll
        for (int k = 0; k < 8; ++k) {
            r[k] = fmaf(acc[k], inv, bias[8 * c + k]);
            if (RELU) r[k] = fmaxf(r[k], 0.f);
        }
        float4* op = (float4*)(out + (size_t)i * FOUT + 8 * c);
        op[0] = make_float4(r[0], r[1], r[2], r[3]);
        op[1] = make_float4(r[4], r[5], r[6], r[7]);
    } else {
        constexpr int VC = FOUT / 8;               // valid lane-chunks (5 for FOUT=40)
        bool act = (c < VC);
        float v[8];
#pragma unroll
        for (int k = 0; k < 8; ++k) {
            float bv = bias[act ? 8 * c + k : 0];
            v[k] = act ? fmaf(acc[k], inv, bv) : -INFINITY;
        }
        float mx = v[0];
#pragma unroll
        for (int k = 1; k < 8; ++k) mx = fmaxf(mx, v[k]);
#pragma unroll
        for (int o = 1; o <= 4; o <<= 1) mx = fmaxf(mx, __shfl_xor(mx, o));  // within 8-lane group
        float es = 0.f;
        if (act) {
#pragma unroll
            for (int k = 0; k < 8; ++k) es += __expf(v[k] - mx);
        }
#pragma unroll
        for (int o = 1; o <= 4; o <<= 1) es += __shfl_xor(es, o);
        if (act) {
            float lse = mx + __logf(es);
            float4* op = (float4*)(out + (size_t)i * FOUT + 8 * c);
            op[0] = make_float4(v[0] - lse, v[1] - lse, v[2] - lse, v[3] - lse);
            op[1] = make_float4(v[4] - lse, v[5] - lse, v[6] - lse, v[7] - lse);
        }
    }
}

// ---------------- launch ----------------

extern "C" void kernel_launch(void* const* d_in, const int* in_sizes, int n_in,
                              void* d_out, int out_size, void* d_ws, size_t ws_size,
                              hipStream_t stream) {
    const float* x   = (const float*)d_in[0];
    const int* edges = (const int*)d_in[1];
    const float* W1  = (const float*)d_in[2];
    const float* av_s1 = (const float*)d_in[3];
    const float* av_d1 = (const float*)d_in[4];
    const float* b1  = (const float*)d_in[5];
    const float* W2  = (const float*)d_in[6];
    const float* av_s2 = (const float*)d_in[7];
    const float* av_d2 = (const float*)d_in[8];
    const float* b2  = (const float*)d_in[9];
    float* out = (float*)d_out;

    const int N  = in_sizes[0] / F_IN;
    const int E  = in_sizes[1] / 2;
    const int Et = E + N;
    const int NB = (N + 255) >> 8;

    char* p = (char*)d_ws;
    auto alloc = [&](size_t bytes) {
        char* q = p;
        p += (bytes + 255) & ~(size_t)255;
        return (void*)q;
    };
    unsigned short* h1 = (unsigned short*)alloc((size_t)N * F_H * 2);  // f16; reused as h2 (padded to 64)
    float* out1   = (float*)alloc((size_t)N * F_H * 4);
    float* as1    = (float*)alloc((size_t)N * 4);
    float* ad1    = (float*)alloc((size_t)N * 4);
    float* as2    = (float*)alloc((size_t)N * 4);
    float* ad2    = (float*)alloc((size_t)N * 4);
    int* rp       = (int*)alloc((size_t)(N + 1) * 4);
    int* bcnt     = (int*)alloc(NBMAX * 4);
    int* bbase    = (int*)alloc(NBMAX * 4);
    int* bcur     = (int*)alloc(NBMAX * 4);
    unsigned* binned = (unsigned*)alloc((size_t)Et * 4);
    int* csr      = (int*)alloc((size_t)Et * 4);
    unsigned short* WhiT = (unsigned short*)alloc((size_t)F_H * F_IN * 2);
    unsigned short* WloT = (unsigned short*)alloc((size_t)F_H * F_IN * 2);
    (void)n_in; (void)out_size; (void)ws_size;

    const int* srcs = edges;
    const int* dsts = edges + E;

    hipMemsetAsync(bcnt, 0, NBMAX * 4, stream);

    k_wsplit<<<(F_IN * F_H + 255) / 256, 256, 0, stream>>>(W1, WhiT, WloT);
    k_binA<<<(Et + 2047) / 2048, 256, 0, stream>>>(dsts, bcnt, E, Et, NB);
    k_binB<<<1, NBMAX, 0, stream>>>(bcnt, bbase, bcur, rp, NB, N, Et);
    k_binC<<<(Et + CHUNK - 1) / CHUNK, 256, 0, stream>>>(srcs, dsts, bcur, binned, E, Et, NB);
    k_binD<<<NB, 256, 0, stream>>>(binned, bbase, bcur, rp, csr, N);

    k_gemm1m<<<(N + 63) / 64, 256, 0, stream>>>(x, WhiT, WloT, av_s1, av_d1, h1, as1, ad1, N);
    int gAgg = (N + 31) / 32;
    k_agg<F_H, true, false><<<gAgg, 256, 0, stream>>>(rp, csr, as1, ad1,
                                                      (const uint4*)h1, b1, out1, N);
    k_gemm2<<<(N + 63) / 64, 256, 0, stream>>>(out1, W2, av_s2, av_d2, h1, as2, ad2, N);
    k_agg<F_O, false, true><<<gAgg, 256, 0, stream>>>(rp, csr, as2, ad2,
                                                      (const uint4*)h1, b2, out, N);
}